// Round 1
// baseline (128.056 us; speedup 1.0000x reference)
//
#include <hip/hip_runtime.h>

// ---------------------------------------------------------------------------
// Why this kernel is a zero-fill:
//
// The reference computes
//     OD        = tanh(a[None,:] + c[:,None] + distance*w + b)   # fp32
//     adjacency = where(OD > 1.0, OD, 0.0)                       # Threshold(1,0)
// and the final output is flows[b, t] = adjacency[cur, nxt].
//
// fp32 tanh (XLA / Eigen clamped rational approximation) satisfies
// |tanh(x)| <= 1.0 for all x — at most it rounds to exactly 1.0f, and
// (1.0 > 1.0) is false. Hence adjacency == 0 everywhere, and the output
// [B=256, STEPS=199, 1] is identically zero regardless of the GAT
// embeddings, the OD matrix, or the Threefry/gumbel random-walk path.
// The whole upstream pipeline is dead code w.r.t. d_out.
//
// The harness poisons d_out with 0xAA before every launch, so we must
// actively write the zeros on every call (same work every call — graph-
// capture safe: one kernel launch on `stream`, no mallocs/syncs).
// ---------------------------------------------------------------------------

__global__ void zero_fill_kernel(float* __restrict__ out, int n) {
    int i = blockIdx.x * blockDim.x + threadIdx.x;
    int i4 = i * 4;
    if (i4 + 3 < n) {
        // coalesced 16B stores: 64 lanes x 16B = 1 KiB per wave instruction
        reinterpret_cast<float4*>(out)[i] = make_float4(0.f, 0.f, 0.f, 0.f);
    } else if (i4 < n) {
        // tail (not hit for n = 50944, but keep it shape-generic)
        for (int j = i4; j < n; ++j) out[j] = 0.f;
    }
}

extern "C" void kernel_launch(void* const* d_in, const int* in_sizes, int n_in,
                              void* d_out, int out_size, void* d_ws, size_t ws_size,
                              hipStream_t stream) {
    // out_size = B * STEPS * 1 = 256 * 199 = 50944 fp32 elements
    float* out = reinterpret_cast<float*>(d_out);
    int n_vec_threads = (out_size + 3) / 4;         // one thread per float4
    int block = 256;
    int grid = (n_vec_threads + block - 1) / block; // 50 blocks for 50944 elems
    zero_fill_kernel<<<grid, block, 0, stream>>>(out, out_size);
}